// Round 8
// baseline (571.862 us; speedup 1.0000x reference)
//
#include <hip/hip_runtime.h>
#include <math.h>

// GAT actor-critic forward on MI355X — 7-launch version.
// L1: [gemm1(MFMA, inline W1 transpose) + edge-histogram + ctrl-zero] fused
// L2: per-digit scan + last-block base257 (ticket pattern)
// L3: bucket scatter (LDS cursors)   L4: per-bucket counting sort -> CSR
// L5: agg1 (chunk-16 softmax gather) L6: gemm2 (MFMA, inline W2 transpose)
// L7: agg2 + actor/critic heads fused (value via 64 padded atomic slots +
//     last-block final reduce). bf16 payloads, fp32 accumulation.

#define TILE 4096

typedef __attribute__((ext_vector_type(8))) short short8;
typedef __attribute__((ext_vector_type(4))) float floatx4;

__device__ __forceinline__ float leaky02(float e){ return e > 0.f ? e : 0.2f*e; }

__device__ __forceinline__ unsigned short f2bf(float f){
    union { float f; unsigned int i; } v; v.f = f;
    unsigned int r = v.i + 0x7fffu + ((v.i >> 16) & 1u);
    return (unsigned short)(r >> 16);
}
__device__ __forceinline__ float bfx(unsigned int g){
    union { unsigned int i; float f; } v; v.i = g << 16; return v.f;
}
__device__ __forceinline__ float bfy(unsigned int g){
    union { unsigned int i; float f; } v; v.i = g & 0xffff0000u; return v.f;
}
__device__ __forceinline__ float bf1(unsigned short u){
    union { unsigned int i; float f; } v; v.i = ((unsigned int)u) << 16; return v.f;
}

// ---------------- L1: gemm1 (MFMA) + edge histogram + ctrl zero ----------------
__global__ __launch_bounds__(256) void k_fused1(const float* __restrict__ x,
        const float* __restrict__ W1,
        const float* __restrict__ aS, const float* __restrict__ aD,
        unsigned short* __restrict__ h1b, float* __restrict__ pAS, float* __restrict__ pAD, int n,
        const int* __restrict__ ei, int e, int e2, int* __restrict__ counts, int nbT, int nbG,
        int* __restrict__ done, int* __restrict__ done2, float* __restrict__ valbuf)
{
    __shared__ unsigned short As[64*136];   // 17.4 KB
    __shared__ unsigned short Bs[128*136];  // 34.8 KB
    const int tid = threadIdx.x;

    if (blockIdx.x >= nbG){
        // -------- histogram part (one tile of TILE edges) --------
        int tb = blockIdx.x - nbG;
        int* h = (int*)As;
        h[tid] = 0; __syncthreads();
        int base = tb*TILE;
        #pragma unroll
        for (int k = 0; k < TILE/256; k++){
            int i = base + k*256 + tid;
            if (i < e2){
                int d = (i < e) ? ei[(size_t)e + i] : (i - e);
                atomicAdd(&h[d >> 8], 1);
            }
        }
        __syncthreads();
        counts[(size_t)tid*nbT + tb] = h[tid];   // transposed: [digit][block]
        return;
    }

    // -------- housekeeping (block 0): zero control buffers --------
    if (blockIdx.x == 0){
        if (tid == 0){ *done = 0; *done2 = 0; }
        for (int i = tid; i < 64*32; i += 256) valbuf[i] = 0.f;
    }

    const int brow = blockIdx.x*64;
    // stage A: x fp32 -> bf16 LDS [row][k]
    {
        int row = tid >> 2, cb = (tid & 3)*32;
        bool ok = brow + row < n;
        #pragma unroll
        for (int i=0;i<8;i++){
            float4 v = ok ? *(const float4*)&x[(size_t)(brow+row)*128 + cb + i*4]
                          : make_float4(0.f,0.f,0.f,0.f);
            ushort4 b = make_ushort4(f2bf(v.x),f2bf(v.y),f2bf(v.z),f2bf(v.w));
            *(ushort4*)&As[row*136 + cb + i*4] = b;
        }
    }
    // stage B: W1 fp32 [k][n] -> bf16 LDS [n][k] (inline transpose+convert)
    {
        #pragma unroll
        for (int j=0;j<16;j++){
            int idx = tid + j*256;          // 4096 float4s
            int k = idx >> 5, nn0 = (idx & 31)*4;
            float4 v = *(const float4*)&W1[(size_t)k*128 + nn0];
            Bs[(nn0+0)*136 + k] = f2bf(v.x);
            Bs[(nn0+1)*136 + k] = f2bf(v.y);
            Bs[(nn0+2)*136 + k] = f2bf(v.z);
            Bs[(nn0+3)*136 + k] = f2bf(v.w);
        }
    }
    __syncthreads();

    const int wv = tid >> 6, lane = tid & 63;
    const int m = lane & 15, quad = lane >> 4;
    floatx4 acc[8];
    #pragma unroll
    for (int i=0;i<8;i++) acc[i] = (floatx4){0.f,0.f,0.f,0.f};

    #pragma unroll
    for (int kc=0; kc<4; kc++){
        int k0 = kc*32 + quad*8;
        short8 a = *(const short8*)&As[(wv*16+m)*136 + k0];
        #pragma unroll
        for (int ct=0; ct<8; ct++){
            short8 b = *(const short8*)&Bs[(ct*16+m)*136 + k0];
            acc[ct] = __builtin_amdgcn_mfma_f32_16x16x32_bf16(a, b, acc[ct], 0,0,0);
        }
    }
    __syncthreads();

    // repack C (bf16) into As as [64][128]
    #pragma unroll
    for (int ct=0; ct<8; ct++){
        #pragma unroll
        for (int r=0;r<4;r++){
            int row = wv*16 + quad*4 + r;
            As[row*128 + ct*16 + m] = f2bf(acc[ct][r]);
        }
    }
    __syncthreads();

    // coalesced global writes + per-(row,head) attention dots
    {
        int row = tid >> 2, hd = tid & 3;
        int grow = brow + row;
        if (grow < n){
            float ps=0.f, pd=0.f;
            #pragma unroll
            for (int i=0;i<4;i++){
                uint4 u = *(const uint4*)&As[row*128 + hd*32 + i*8];
                *(uint4*)&h1b[(size_t)grow*128 + hd*32 + i*8] = u;
                unsigned int uw[4] = {u.x,u.y,u.z,u.w};
                #pragma unroll
                for (int j=0;j<4;j++){
                    float c0 = bfx(uw[j]), c1 = bfy(uw[j]);
                    int cc = hd*32 + i*8 + j*2;
                    ps += c0*aS[cc] + c1*aS[cc+1];
                    pd += c0*aD[cc] + c1*aD[cc+1];
                }
            }
            pAS[grow*4+hd] = ps;
            pAD[grow*4+hd] = pd;
        }
    }
}

// ---------------- L2: per-digit scan over blocks + last-block base257 ----------------
__global__ __launch_bounds__(256) void k_scan(int* __restrict__ counts, int nb,
        int* __restrict__ digTot, int* __restrict__ base257, int* __restrict__ done)
{
    __shared__ int sb[256];
    __shared__ int lastF;
    const int t = blockIdx.x;       // digit
    const int i = threadIdx.x;
    int carry = 0;
    for (int c0 = 0; c0 < nb; c0 += 256){
        int idx = c0 + i;
        int v = (idx < nb) ? counts[(size_t)t*nb + idx] : 0;
        sb[i] = v; __syncthreads();
        for (int off = 1; off < 256; off <<= 1){
            int u = (i >= off) ? sb[i-off] : 0;
            __syncthreads();
            if (i >= off) sb[i] += u;
            __syncthreads();
        }
        if (idx < nb) counts[(size_t)t*nb + idx] = carry + sb[i] - v;  // exclusive
        int tot = sb[255];
        __syncthreads();
        carry += tot;
    }
    if (i == 0){
        atomicExch(&digTot[t], carry);
        __threadfence();
        int tk = atomicAdd(done, 1);
        lastF = (tk == 255);
    }
    __syncthreads();
    if (lastF){
        __threadfence();
        int v = atomicAdd(&digTot[i], 0);   // coherent read
        sb[i] = v; __syncthreads();
        for (int off = 1; off < 256; off <<= 1){
            int u = (i >= off) ? sb[i-off] : 0;
            __syncthreads();
            if (i >= off) sb[i] += u;
            __syncthreads();
        }
        base257[i] = sb[i] - v;
        if (i == 255) base257[256] = sb[255];
    }
}

// ---------------- L3: scatter into buckets (LDS cursors, no global atomics) ----------------
__global__ __launch_bounds__(256) void k_bucket(const int* __restrict__ ei, int e, int e2,
        const int* __restrict__ counts, int nbT, const int* __restrict__ base257,
        unsigned int* __restrict__ buck)
{
    __shared__ int curs[256];
    int t = threadIdx.x;
    curs[t] = counts[(size_t)t*nbT + blockIdx.x] + base257[t];
    __syncthreads();
    int base = blockIdx.x*TILE;
    #pragma unroll
    for (int k = 0; k < TILE/256; k++){
        int i = base + k*256 + t;
        if (i < e2){
            int s, d;
            if (i < e){ s = ei[i]; d = ei[(size_t)e + i]; }
            else      { s = i - e; d = i - e; }
            int p = atomicAdd(&curs[d >> 8], 1);
            buck[p] = ((unsigned int)d << 16) | (unsigned int)s;
        }
    }
}

// ---------------- L4: per-bucket counting sort -> csr + rs/re ----------------
__global__ __launch_bounds__(256) void k_p2(const unsigned int* __restrict__ buck,
        const int* __restrict__ base257, int n,
        int* __restrict__ csr, int* __restrict__ rs, int* __restrict__ re)
{
    __shared__ int bins[256], sc[256], curs[256];
    const int b = blockIdx.x, t = threadIdx.x;
    const int lo = base257[b], hi = base257[b+1];
    bins[t] = 0; __syncthreads();
    for (int i = lo + t; i < hi; i += 256){
        int dg = (buck[i] >> 16) & 0xFF;
        atomicAdd(&bins[dg], 1);
    }
    __syncthreads();
    sc[t] = bins[t]; __syncthreads();
    for (int off = 1; off < 256; off <<= 1){
        int v = (t >= off) ? sc[t-off] : 0;
        __syncthreads();
        if (t >= off) sc[t] += v;
        __syncthreads();
    }
    int sInc = sc[t];
    int node = b*256 + t;
    if (node < n){
        rs[node] = lo + sInc - bins[t];
        re[node] = lo + sInc;
    }
    curs[t] = lo + sInc - bins[t];
    __syncthreads();
    for (int i = lo + t; i < hi; i += 256){
        unsigned int pk = buck[i];
        int p = atomicAdd(&curs[(pk >> 16) & 0xFF], 1);
        csr[p] = (int)(pk & 0xFFFFu);
    }
}

// ---------------- L5: agg1 — chunk-16, lane-parallel exp, 16-deep gather ----------------
__global__ __launch_bounds__(256) void k_agg1(const int* __restrict__ rs, const int* __restrict__ re,
        const int* __restrict__ csr, const float* __restrict__ as1, const float* __restrict__ ad1,
        const unsigned short* __restrict__ h1b, const float* __restrict__ b1,
        unsigned short* __restrict__ h1ob, int n)
{
    const int lane = threadIdx.x & 63;
    const int node = blockIdx.x*4 + (threadIdx.x >> 6);
    if (node >= n) return;
    const int h   = lane >> 4;
    const int f   = lane*2;
    const int j16 = lane & 15;
    const int grp = lane & 48;
    const float adv = ad1[node*4 + h];
    const int start = rs[node], end = re[node];
    const unsigned int* hp = (const unsigned int*)h1b + (f >> 1);  // index s*64

    float den = 0.f, ax = 0.f, ay = 0.f;
    int i0 = start;

    for (; i0 + 16 <= end; i0 += 16){
        int sj = csr[i0 + j16];
        float e = __expf(leaky02(as1[sj*4 + h] + adv));
        den += e;
        #pragma unroll
        for (int j = 0; j < 16; j++){
            float ej = __shfl(e,  grp + j, 64);
            int   s2 = __shfl(sj, grp + j, 64);
            unsigned int g = hp[s2*64];
            ax += ej*bfx(g); ay += ej*bfy(g);
        }
    }
    int c = end - i0;
    if (c > 0){
        int jj = (j16 < c) ? j16 : (c-1);
        int sj = csr[i0 + jj];
        float e = __expf(leaky02(as1[sj*4 + h] + adv));
        if (j16 < c) den += e;
        for (int j = 0; j < c; j += 4){
            #pragma unroll
            for (int u = 0; u < 4; u++){
                int je = j + u;
                int jc = (je < c) ? je : (c-1);
                float ej = __shfl(e,  grp + jc, 64);
                int   s2 = __shfl(sj, grp + jc, 64);
                ej = (je < c) ? ej : 0.f;
                unsigned int g = hp[s2*64];
                ax += ej*bfx(g); ay += ej*bfy(g);
            }
        }
    }
    den += __shfl_xor(den, 1, 64);
    den += __shfl_xor(den, 2, 64);
    den += __shfl_xor(den, 4, 64);
    den += __shfl_xor(den, 8, 64);

    float ox = ax/den + b1[f];
    float oy = ay/den + b1[f+1];
    ox = ox > 0.f ? ox : expm1f(ox);
    oy = oy > 0.f ? oy : expm1f(oy);
    unsigned int pk = (unsigned int)f2bf(ox) | ((unsigned int)f2bf(oy) << 16);
    *(unsigned int*)&h1ob[(size_t)node*128 + f] = pk;
}

// ---------------- L6: gemm2 (MFMA, inline W2 transpose) ----------------
__global__ __launch_bounds__(256) void k_gemm2(const unsigned short* __restrict__ h1ob,
        const float* __restrict__ W2,
        const float* __restrict__ aS, const float* __restrict__ aD,
        unsigned short* __restrict__ h2pb, float* __restrict__ pAS, float* __restrict__ pAD, int n)
{
    __shared__ unsigned short As[64*136];   // 17.4 KB
    __shared__ unsigned short Bs[32*136];   // 8.7 KB
    const int tid  = threadIdx.x;
    const int brow = blockIdx.x*64;

    {   // stage A (already bf16)
        int row = tid >> 2, cb = (tid & 3)*32;
        bool ok = brow + row < n;
        #pragma unroll
        for (int i=0;i<4;i++){
            uint4 v = ok ? *(const uint4*)&h1ob[(size_t)(brow+row)*128 + cb + i*8]
                         : make_uint4(0,0,0,0);
            *(uint4*)&As[row*136 + cb + i*8] = v;
        }
    }
    {   // stage B: W2 fp32 [k][32] -> bf16 LDS [n][k]
        #pragma unroll
        for (int j=0;j<4;j++){
            int idx = tid + j*256;          // 1024 float4s
            int k = idx >> 3, nn0 = (idx & 7)*4;
            float4 v = *(const float4*)&W2[(size_t)k*32 + nn0];
            Bs[(nn0+0)*136 + k] = f2bf(v.x);
            Bs[(nn0+1)*136 + k] = f2bf(v.y);
            Bs[(nn0+2)*136 + k] = f2bf(v.z);
            Bs[(nn0+3)*136 + k] = f2bf(v.w);
        }
    }
    __syncthreads();

    const int wv = tid >> 6, lane = tid & 63;
    const int m = lane & 15, quad = lane >> 4;
    floatx4 acc[2];
    acc[0] = (floatx4){0.f,0.f,0.f,0.f};
    acc[1] = (floatx4){0.f,0.f,0.f,0.f};

    #pragma unroll
    for (int kc=0; kc<4; kc++){
        int k0 = kc*32 + quad*8;
        short8 a = *(const short8*)&As[(wv*16+m)*136 + k0];
        #pragma unroll
        for (int ct=0; ct<2; ct++){
            short8 b = *(const short8*)&Bs[(ct*16+m)*136 + k0];
            acc[ct] = __builtin_amdgcn_mfma_f32_16x16x32_bf16(a, b, acc[ct], 0,0,0);
        }
    }
    __syncthreads();

    #pragma unroll
    for (int ct=0; ct<2; ct++){
        #pragma unroll
        for (int r=0;r<4;r++){
            int row = wv*16 + quad*4 + r;
            As[row*32 + ct*16 + m] = f2bf(acc[ct][r]);
        }
    }
    __syncthreads();

    if (tid < 64){
        int grow = brow + tid;
        if (grow < n){
            float ps=0.f, pd=0.f;
            #pragma unroll
            for (int i=0;i<4;i++){
                uint4 u = *(const uint4*)&As[tid*32 + i*8];
                *(uint4*)&h2pb[(size_t)grow*32 + i*8] = u;
                unsigned int uw[4] = {u.x,u.y,u.z,u.w};
                #pragma unroll
                for (int j=0;j<4;j++){
                    float c0 = bfx(uw[j]), c1 = bfy(uw[j]);
                    int cc = i*8 + j*2;
                    ps += c0*aS[cc] + c1*aS[cc+1];
                    pd += c0*aD[cc] + c1*aD[cc+1];
                }
            }
            pAS[grow] = ps;
            pAD[grow] = pd;
        }
    }
}

// ---------------- L7: agg2 + actor/critic heads fused ----------------
__global__ __launch_bounds__(256) void k_agg2h(const int* __restrict__ rs, const int* __restrict__ re,
        const int* __restrict__ csr, const float* __restrict__ as2, const float* __restrict__ ad2,
        const unsigned short* __restrict__ h2pb, const float* __restrict__ b2,
        const float* __restrict__ Wa, const float* __restrict__ ba, const float* __restrict__ Wc,
        const float* __restrict__ bc, int n, float* __restrict__ out,
        float* __restrict__ valbuf, int* __restrict__ done2, int nblocks)
{
    __shared__ float WaS[1024], WcS[32], baS[32], b2S[32];
    __shared__ float h2s[4*32], vpart[4], logit_s[128];
    __shared__ int lastF;
    const int tid = threadIdx.x;

    *(float4*)&WaS[tid*4] = *(const float4*)&Wa[tid*4];
    if (tid < 32){ WcS[tid] = Wc[tid]; baS[tid] = ba[tid]; b2S[tid] = b2[tid]; }
    __syncthreads();

    const int lane = tid & 63, wv = tid >> 6;
    const int node = blockIdx.x*4 + wv;
    const int f    = lane & 31;
    const int half = lane >> 5;
    const int j16  = lane & 15;
    const int grp  = lane & 48;
    const bool valid = node < n;

    float den = 0.f, acc = 0.f;
    if (valid){
        const float adv = ad2[node];
        const int start = rs[node], end = re[node];
        const unsigned short* hp = h2pb + f;
        int i0 = start;
        for (; i0 + 16 <= end; i0 += 16){
            int sj = csr[i0 + j16];
            float e = __expf(leaky02(as2[sj] + adv));
            den += e;
            #pragma unroll
            for (int jj = 0; jj < 8; jj++){
                int j = 2*jj + half;
                float ej = __shfl(e,  grp + j, 64);
                int   s2 = __shfl(sj, grp + j, 64);
                acc += ej * bf1(hp[s2*32]);
            }
        }
        int c = end - i0;
        if (c > 0){
            int jj = (j16 < c) ? j16 : (c-1);
            int sj = csr[i0 + jj];
            float e = __expf(leaky02(as2[sj] + adv));
            if (j16 < c) den += e;
            for (int j = half; j < c; j += 8){
                #pragma unroll
                for (int u = 0; u < 4; u++){
                    int je = j + 2*u;
                    int jc = (je < c) ? je : (c-1);
                    float ej = __shfl(e,  grp + (jc & 15), 64);
                    int   s2 = __shfl(sj, grp + (jc & 15), 64);
                    ej = (je < c) ? ej : 0.f;
                    acc += ej * bf1(hp[s2*32]);
                }
            }
        }
    }
    den += __shfl_xor(den, 1, 64);
    den += __shfl_xor(den, 2, 64);
    den += __shfl_xor(den, 4, 64);
    den += __shfl_xor(den, 8, 64);
    acc += __shfl_xor(acc, 32, 64);

    if (valid && half == 0){
        float o = acc/den + b2S[f];
        o = o > 0.f ? o : expm1f(o);
        h2s[wv*32 + f] = o;           // same-wave LDS write; read below by all 64 lanes
    }

    // value partial: lanes of half 0 reduce h2·Wc
    {
        float t = 0.f;
        if (valid && half == 0) t = h2s[wv*32 + f] * WcS[f];
        t += __shfl_xor(t, 1, 64);
        t += __shfl_xor(t, 2, 64);
        t += __shfl_xor(t, 4, 64);
        t += __shfl_xor(t, 8, 64);
        t += __shfl_xor(t, 16, 64);
        if (lane == 0) vpart[wv] = valid ? t : 0.f;
    }

    // logits: agent a = lane&31; each half does 16 channels, combine across halves
    {
        float pa = 0.f;
        if (valid){
            int a = lane & 31;
            #pragma unroll
            for (int cc = 0; cc < 16; cc++){
                int c = half*16 + cc;
                pa += h2s[wv*32 + c] * WaS[c*32 + a];
            }
        }
        pa += __shfl_xor(pa, 32, 64);
        if (valid && half == 0) logit_s[wv*32 + (lane & 31)] = pa + baS[lane & 31];
    }
    __syncthreads();

    // coalesced-ish store: 16B chunks (4 consecutive nodes per agent)
    if (tid < 128){
        int a = tid >> 2, nd = tid & 3;
        int nodeS = blockIdx.x*4 + nd;
        if (nodeS < n) out[(size_t)a*n + nodeS] = logit_s[nd*32 + a];
    }
    if (tid == 0){
        float bp = vpart[0] + vpart[1] + vpart[2] + vpart[3];
        atomicAdd(&valbuf[(blockIdx.x & 63)*32], bp);
        __threadfence();
        int tk = atomicAdd(done2, 1);
        lastF = (tk == nblocks - 1);
    }
    __syncthreads();
    if (lastF && tid < 64){
        __threadfence();
        float v = atomicAdd(&valbuf[tid*32], 0.f);   // coherent read
        v += __shfl_xor(v, 1, 64);
        v += __shfl_xor(v, 2, 64);
        v += __shfl_xor(v, 4, 64);
        v += __shfl_xor(v, 8, 64);
        v += __shfl_xor(v, 16, 64);
        v += __shfl_xor(v, 32, 64);
        if (tid == 0) out[(size_t)32*n] = v*(1.0f/n) + bc[0];
    }
}

extern "C" void kernel_launch(void* const* d_in, const int* in_sizes, int n_in,
                              void* d_out, int out_size, void* d_ws, size_t ws_size,
                              hipStream_t stream)
{
    const float* x   = (const float*)d_in[0];
    const int*   ei  = (const int*)d_in[1];
    const float* W1  = (const float*)d_in[2];
    const float* a1s = (const float*)d_in[3];
    const float* a1d = (const float*)d_in[4];
    const float* b1  = (const float*)d_in[5];
    const float* W2  = (const float*)d_in[6];
    const float* a2s = (const float*)d_in[7];
    const float* a2d = (const float*)d_in[8];
    const float* b2  = (const float*)d_in[9];
    const float* Wa  = (const float*)d_in[10];
    const float* ba  = (const float*)d_in[11];
    const float* Wc  = (const float*)d_in[12];
    const float* bc  = (const float*)d_in[13];
    float* out = (float*)d_out;

    const int N  = in_sizes[0] / 128;
    const int E  = in_sizes[1] / 2;
    const int E2 = E + N;
    const int nbT = (E2 + TILE - 1) / TILE;   // sort tiles
    const int nbB = (N + 255) / 256;          // buckets
    const int nbG = (N + 63) / 64;            // gemm blocks
    const int nbAgg = (N + 3) / 4;            // agg blocks

    // workspace layout (256B-aligned chunks)
    char* base = (char*)d_ws;
    auto alloc = [&](size_t bytes) -> char* {
        char* p = base; base += (bytes + 255) & ~(size_t)255; return p;
    };
    float* as1    = (float*)alloc((size_t)N*4*4);
    float* ad1    = (float*)alloc((size_t)N*4*4);
    float* as2    = (float*)alloc((size_t)N*4);
    float* ad2    = (float*)alloc((size_t)N*4);
    int* counts   = (int*)alloc((size_t)nbT*256*4);
    int* digTot   = (int*)alloc(256*4);
    int* base257  = (int*)alloc(257*4);
    int* done     = (int*)alloc(256);
    int* done2    = (int*)alloc(256);
    float* valbuf = (float*)alloc(64*32*4);
    int* rs       = (int*)alloc((size_t)N*4);
    int* re       = (int*)alloc((size_t)N*4);
    int* csr      = (int*)alloc((size_t)E2*4);
    unsigned int* buck = (unsigned int*)alloc((size_t)E2*4);
    unsigned short* h1b  = (unsigned short*)alloc((size_t)N*128*2);
    unsigned short* h1ob = (unsigned short*)alloc((size_t)N*128*2);
    unsigned short* h2pb = (unsigned short*)alloc((size_t)N*32*2);

    k_fused1<<<nbG + nbT, 256, 0, stream>>>(x, W1, a1s, a1d, h1b, as1, ad1, N,
                                            ei, E, E2, counts, nbT, nbG, done, done2, valbuf);
    k_scan<<<256, 256, 0, stream>>>(counts, nbT, digTot, base257, done);
    k_bucket<<<nbT, 256, 0, stream>>>(ei, E, E2, counts, nbT, base257, buck);
    k_p2<<<nbB, 256, 0, stream>>>(buck, base257, N, csr, rs, re);
    k_agg1<<<nbAgg, 256, 0, stream>>>(rs, re, csr, as1, ad1, h1b, b1, h1ob, N);
    k_gemm2<<<nbG, 256, 0, stream>>>(h1ob, W2, a2s, a2d, h2pb, as2, ad2, N);
    k_agg2h<<<nbAgg, 256, 0, stream>>>(rs, re, csr, as2, ad2, h2pb, b2,
                                       Wa, ba, Wc, bc, N, out, valbuf, done2, nbAgg);
}

// Round 9
// 237.799 us; speedup vs baseline: 2.4048x; 2.4048x over previous
//
#include <hip/hip_runtime.h>
#include <math.h>

// GAT actor-critic forward on MI355X — 8-launch version.
// L1: [gemm1(MFMA, inline W1 transpose) + edge-histogram + ctrl-zero] fused
// L2: per-digit scan + last-block base257 (ticket; 256 blocks so fence is cheap)
// L3: bucket scatter (LDS cursors)   L4: per-bucket counting sort -> CSR
// L5: agg1 (chunk-16 softmax gather) L6: gemm2 (MFMA, inline W2 transpose)
// L7: agg2 + heads fused; value partials via fire-and-forget atomics (NO fence
//     — per-block __threadfence = L2 writeback on CDNA4, was a 378us disaster)
// L8: k_val<<<1,64>>> final value reduce (atomic reads, cross-XCD safe).

#define TILE 4096

typedef __attribute__((ext_vector_type(8))) short short8;
typedef __attribute__((ext_vector_type(4))) float floatx4;

__device__ __forceinline__ float leaky02(float e){ return e > 0.f ? e : 0.2f*e; }

__device__ __forceinline__ unsigned short f2bf(float f){
    union { float f; unsigned int i; } v; v.f = f;
    unsigned int r = v.i + 0x7fffu + ((v.i >> 16) & 1u);
    return (unsigned short)(r >> 16);
}
__device__ __forceinline__ float bfx(unsigned int g){
    union { unsigned int i; float f; } v; v.i = g << 16; return v.f;
}
__device__ __forceinline__ float bfy(unsigned int g){
    union { unsigned int i; float f; } v; v.i = g & 0xffff0000u; return v.f;
}
__device__ __forceinline__ float bf1(unsigned short u){
    union { unsigned int i; float f; } v; v.i = ((unsigned int)u) << 16; return v.f;
}

// ---------------- L1: gemm1 (MFMA) + edge histogram + ctrl zero ----------------
__global__ __launch_bounds__(256) void k_fused1(const float* __restrict__ x,
        const float* __restrict__ W1,
        const float* __restrict__ aS, const float* __restrict__ aD,
        unsigned short* __restrict__ h1b, float* __restrict__ pAS, float* __restrict__ pAD, int n,
        const int* __restrict__ ei, int e, int e2, int* __restrict__ counts, int nbT, int nbG,
        int* __restrict__ done, float* __restrict__ valbuf)
{
    __shared__ unsigned short As[64*136];   // 17.4 KB
    __shared__ unsigned short Bs[128*136];  // 34.8 KB
    const int tid = threadIdx.x;

    if (blockIdx.x >= nbG){
        // -------- histogram part (one tile of TILE edges) --------
        int tb = blockIdx.x - nbG;
        int* h = (int*)As;
        h[tid] = 0; __syncthreads();
        int base = tb*TILE;
        #pragma unroll
        for (int k = 0; k < TILE/256; k++){
            int i = base + k*256 + tid;
            if (i < e2){
                int d = (i < e) ? ei[(size_t)e + i] : (i - e);
                atomicAdd(&h[d >> 8], 1);
            }
        }
        __syncthreads();
        counts[(size_t)tid*nbT + tb] = h[tid];   // transposed: [digit][block]
        return;
    }

    // -------- housekeeping (block 0): zero control buffers --------
    if (blockIdx.x == 0){
        if (tid == 0){ *done = 0; }
        for (int i = tid; i < 64*32; i += 256) valbuf[i] = 0.f;
    }

    const int brow = blockIdx.x*64;
    // stage A: x fp32 -> bf16 LDS [row][k]
    {
        int row = tid >> 2, cb = (tid & 3)*32;
        bool ok = brow + row < n;
        #pragma unroll
        for (int i=0;i<8;i++){
            float4 v = ok ? *(const float4*)&x[(size_t)(brow+row)*128 + cb + i*4]
                          : make_float4(0.f,0.f,0.f,0.f);
            ushort4 b = make_ushort4(f2bf(v.x),f2bf(v.y),f2bf(v.z),f2bf(v.w));
            *(ushort4*)&As[row*136 + cb + i*4] = b;
        }
    }
    // stage B: W1 fp32 [k][n] -> bf16 LDS [n][k] (inline transpose+convert)
    {
        #pragma unroll
        for (int j=0;j<16;j++){
            int idx = tid + j*256;          // 4096 float4s
            int k = idx >> 5, nn0 = (idx & 31)*4;
            float4 v = *(const float4*)&W1[(size_t)k*128 + nn0];
            Bs[(nn0+0)*136 + k] = f2bf(v.x);
            Bs[(nn0+1)*136 + k] = f2bf(v.y);
            Bs[(nn0+2)*136 + k] = f2bf(v.z);
            Bs[(nn0+3)*136 + k] = f2bf(v.w);
        }
    }
    __syncthreads();

    const int wv = tid >> 6, lane = tid & 63;
    const int m = lane & 15, quad = lane >> 4;
    floatx4 acc[8];
    #pragma unroll
    for (int i=0;i<8;i++) acc[i] = (floatx4){0.f,0.f,0.f,0.f};

    #pragma unroll
    for (int kc=0; kc<4; kc++){
        int k0 = kc*32 + quad*8;
        short8 a = *(const short8*)&As[(wv*16+m)*136 + k0];
        #pragma unroll
        for (int ct=0; ct<8; ct++){
            short8 b = *(const short8*)&Bs[(ct*16+m)*136 + k0];
            acc[ct] = __builtin_amdgcn_mfma_f32_16x16x32_bf16(a, b, acc[ct], 0,0,0);
        }
    }
    __syncthreads();

    // repack C (bf16) into As as [64][128]
    #pragma unroll
    for (int ct=0; ct<8; ct++){
        #pragma unroll
        for (int r=0;r<4;r++){
            int row = wv*16 + quad*4 + r;
            As[row*128 + ct*16 + m] = f2bf(acc[ct][r]);
        }
    }
    __syncthreads();

    // coalesced global writes + per-(row,head) attention dots
    {
        int row = tid >> 2, hd = tid & 3;
        int grow = brow + row;
        if (grow < n){
            float ps=0.f, pd=0.f;
            #pragma unroll
            for (int i=0;i<4;i++){
                uint4 u = *(const uint4*)&As[row*128 + hd*32 + i*8];
                *(uint4*)&h1b[(size_t)grow*128 + hd*32 + i*8] = u;
                unsigned int uw[4] = {u.x,u.y,u.z,u.w};
                #pragma unroll
                for (int j=0;j<4;j++){
                    float c0 = bfx(uw[j]), c1 = bfy(uw[j]);
                    int cc = hd*32 + i*8 + j*2;
                    ps += c0*aS[cc] + c1*aS[cc+1];
                    pd += c0*aD[cc] + c1*aD[cc+1];
                }
            }
            pAS[grow*4+hd] = ps;
            pAD[grow*4+hd] = pd;
        }
    }
}

// ---------------- L2: per-digit scan over blocks + last-block base257 ----------------
__global__ __launch_bounds__(256) void k_scan(int* __restrict__ counts, int nb,
        int* __restrict__ digTot, int* __restrict__ base257, int* __restrict__ done)
{
    __shared__ int sb[256];
    __shared__ int lastF;
    const int t = blockIdx.x;       // digit
    const int i = threadIdx.x;
    int carry = 0;
    for (int c0 = 0; c0 < nb; c0 += 256){
        int idx = c0 + i;
        int v = (idx < nb) ? counts[(size_t)t*nb + idx] : 0;
        sb[i] = v; __syncthreads();
        for (int off = 1; off < 256; off <<= 1){
            int u = (i >= off) ? sb[i-off] : 0;
            __syncthreads();
            if (i >= off) sb[i] += u;
            __syncthreads();
        }
        if (idx < nb) counts[(size_t)t*nb + idx] = carry + sb[i] - v;  // exclusive
        int tot = sb[255];
        __syncthreads();
        carry += tot;
    }
    if (i == 0){
        atomicExch(&digTot[t], carry);
        __threadfence();             // 256 blocks only — cheap here
        int tk = atomicAdd(done, 1);
        lastF = (tk == 255);
    }
    __syncthreads();
    if (lastF){
        __threadfence();
        int v = atomicAdd(&digTot[i], 0);   // coherent read
        sb[i] = v; __syncthreads();
        for (int off = 1; off < 256; off <<= 1){
            int u = (i >= off) ? sb[i-off] : 0;
            __syncthreads();
            if (i >= off) sb[i] += u;
            __syncthreads();
        }
        base257[i] = sb[i] - v;
        if (i == 255) base257[256] = sb[255];
    }
}

// ---------------- L3: scatter into buckets (LDS cursors, no global atomics) ----------------
__global__ __launch_bounds__(256) void k_bucket(const int* __restrict__ ei, int e, int e2,
        const int* __restrict__ counts, int nbT, const int* __restrict__ base257,
        unsigned int* __restrict__ buck)
{
    __shared__ int curs[256];
    int t = threadIdx.x;
    curs[t] = counts[(size_t)t*nbT + blockIdx.x] + base257[t];
    __syncthreads();
    int base = blockIdx.x*TILE;
    #pragma unroll
    for (int k = 0; k < TILE/256; k++){
        int i = base + k*256 + t;
        if (i < e2){
            int s, d;
            if (i < e){ s = ei[i]; d = ei[(size_t)e + i]; }
            else      { s = i - e; d = i - e; }
            int p = atomicAdd(&curs[d >> 8], 1);
            buck[p] = ((unsigned int)d << 16) | (unsigned int)s;
        }
    }
}

// ---------------- L4: per-bucket counting sort -> csr + rs/re ----------------
__global__ __launch_bounds__(256) void k_p2(const unsigned int* __restrict__ buck,
        const int* __restrict__ base257, int n,
        int* __restrict__ csr, int* __restrict__ rs, int* __restrict__ re)
{
    __shared__ int bins[256], sc[256], curs[256];
    const int b = blockIdx.x, t = threadIdx.x;
    const int lo = base257[b], hi = base257[b+1];
    bins[t] = 0; __syncthreads();
    for (int i = lo + t; i < hi; i += 256){
        int dg = (buck[i] >> 16) & 0xFF;
        atomicAdd(&bins[dg], 1);
    }
    __syncthreads();
    sc[t] = bins[t]; __syncthreads();
    for (int off = 1; off < 256; off <<= 1){
        int v = (t >= off) ? sc[t-off] : 0;
        __syncthreads();
        if (t >= off) sc[t] += v;
        __syncthreads();
    }
    int sInc = sc[t];
    int node = b*256 + t;
    if (node < n){
        rs[node] = lo + sInc - bins[t];
        re[node] = lo + sInc;
    }
    curs[t] = lo + sInc - bins[t];
    __syncthreads();
    for (int i = lo + t; i < hi; i += 256){
        unsigned int pk = buck[i];
        int p = atomicAdd(&curs[(pk >> 16) & 0xFF], 1);
        csr[p] = (int)(pk & 0xFFFFu);
    }
}

// ---------------- L5: agg1 — chunk-16, lane-parallel exp, 16-deep gather ----------------
__global__ __launch_bounds__(256) void k_agg1(const int* __restrict__ rs, const int* __restrict__ re,
        const int* __restrict__ csr, const float* __restrict__ as1, const float* __restrict__ ad1,
        const unsigned short* __restrict__ h1b, const float* __restrict__ b1,
        unsigned short* __restrict__ h1ob, int n)
{
    const int lane = threadIdx.x & 63;
    const int node = blockIdx.x*4 + (threadIdx.x >> 6);
    if (node >= n) return;
    const int h   = lane >> 4;
    const int f   = lane*2;
    const int j16 = lane & 15;
    const int grp = lane & 48;
    const float adv = ad1[node*4 + h];
    const int start = rs[node], end = re[node];
    const unsigned int* hp = (const unsigned int*)h1b + (f >> 1);  // index s*64

    float den = 0.f, ax = 0.f, ay = 0.f;
    int i0 = start;

    for (; i0 + 16 <= end; i0 += 16){
        int sj = csr[i0 + j16];
        float e = __expf(leaky02(as1[sj*4 + h] + adv));
        den += e;
        #pragma unroll
        for (int j = 0; j < 16; j++){
            float ej = __shfl(e,  grp + j, 64);
            int   s2 = __shfl(sj, grp + j, 64);
            unsigned int g = hp[s2*64];
            ax += ej*bfx(g); ay += ej*bfy(g);
        }
    }
    int c = end - i0;
    if (c > 0){
        int jj = (j16 < c) ? j16 : (c-1);
        int sj = csr[i0 + jj];
        float e = __expf(leaky02(as1[sj*4 + h] + adv));
        if (j16 < c) den += e;
        for (int j = 0; j < c; j += 4){
            #pragma unroll
            for (int u = 0; u < 4; u++){
                int je = j + u;
                int jc = (je < c) ? je : (c-1);
                float ej = __shfl(e,  grp + jc, 64);
                int   s2 = __shfl(sj, grp + jc, 64);
                ej = (je < c) ? ej : 0.f;
                unsigned int g = hp[s2*64];
                ax += ej*bfx(g); ay += ej*bfy(g);
            }
        }
    }
    den += __shfl_xor(den, 1, 64);
    den += __shfl_xor(den, 2, 64);
    den += __shfl_xor(den, 4, 64);
    den += __shfl_xor(den, 8, 64);

    float ox = ax/den + b1[f];
    float oy = ay/den + b1[f+1];
    ox = ox > 0.f ? ox : expm1f(ox);
    oy = oy > 0.f ? oy : expm1f(oy);
    unsigned int pk = (unsigned int)f2bf(ox) | ((unsigned int)f2bf(oy) << 16);
    *(unsigned int*)&h1ob[(size_t)node*128 + f] = pk;
}

// ---------------- L6: gemm2 (MFMA, inline W2 transpose) ----------------
__global__ __launch_bounds__(256) void k_gemm2(const unsigned short* __restrict__ h1ob,
        const float* __restrict__ W2,
        const float* __restrict__ aS, const float* __restrict__ aD,
        unsigned short* __restrict__ h2pb, float* __restrict__ pAS, float* __restrict__ pAD, int n)
{
    __shared__ unsigned short As[64*136];   // 17.4 KB
    __shared__ unsigned short Bs[32*136];   // 8.7 KB
    const int tid  = threadIdx.x;
    const int brow = blockIdx.x*64;

    {   // stage A (already bf16)
        int row = tid >> 2, cb = (tid & 3)*32;
        bool ok = brow + row < n;
        #pragma unroll
        for (int i=0;i<4;i++){
            uint4 v = ok ? *(const uint4*)&h1ob[(size_t)(brow+row)*128 + cb + i*8]
                         : make_uint4(0,0,0,0);
            *(uint4*)&As[row*136 + cb + i*8] = v;
        }
    }
    {   // stage B: W2 fp32 [k][32] -> bf16 LDS [n][k]
        #pragma unroll
        for (int j=0;j<4;j++){
            int idx = tid + j*256;          // 1024 float4s
            int k = idx >> 3, nn0 = (idx & 7)*4;
            float4 v = *(const float4*)&W2[(size_t)k*32 + nn0];
            Bs[(nn0+0)*136 + k] = f2bf(v.x);
            Bs[(nn0+1)*136 + k] = f2bf(v.y);
            Bs[(nn0+2)*136 + k] = f2bf(v.z);
            Bs[(nn0+3)*136 + k] = f2bf(v.w);
        }
    }
    __syncthreads();

    const int wv = tid >> 6, lane = tid & 63;
    const int m = lane & 15, quad = lane >> 4;
    floatx4 acc[2];
    acc[0] = (floatx4){0.f,0.f,0.f,0.f};
    acc[1] = (floatx4){0.f,0.f,0.f,0.f};

    #pragma unroll
    for (int kc=0; kc<4; kc++){
        int k0 = kc*32 + quad*8;
        short8 a = *(const short8*)&As[(wv*16+m)*136 + k0];
        #pragma unroll
        for (int ct=0; ct<2; ct++){
            short8 b = *(const short8*)&Bs[(ct*16+m)*136 + k0];
            acc[ct] = __builtin_amdgcn_mfma_f32_16x16x32_bf16(a, b, acc[ct], 0,0,0);
        }
    }
    __syncthreads();

    #pragma unroll
    for (int ct=0; ct<2; ct++){
        #pragma unroll
        for (int r=0;r<4;r++){
            int row = wv*16 + quad*4 + r;
            As[row*32 + ct*16 + m] = f2bf(acc[ct][r]);
        }
    }
    __syncthreads();

    if (tid < 64){
        int grow = brow + tid;
        if (grow < n){
            float ps=0.f, pd=0.f;
            #pragma unroll
            for (int i=0;i<4;i++){
                uint4 u = *(const uint4*)&As[tid*32 + i*8];
                *(uint4*)&h2pb[(size_t)grow*32 + i*8] = u;
                unsigned int uw[4] = {u.x,u.y,u.z,u.w};
                #pragma unroll
                for (int j=0;j<4;j++){
                    float c0 = bfx(uw[j]), c1 = bfy(uw[j]);
                    int cc = i*8 + j*2;
                    ps += c0*aS[cc] + c1*aS[cc+1];
                    pd += c0*aD[cc] + c1*aD[cc+1];
                }
            }
            pAS[grow] = ps;
            pAD[grow] = pd;
        }
    }
}

// ---------------- L7: agg2 + actor/critic heads fused (no fences) ----------------
__global__ __launch_bounds__(256) void k_agg2h(const int* __restrict__ rs, const int* __restrict__ re,
        const int* __restrict__ csr, const float* __restrict__ as2, const float* __restrict__ ad2,
        const unsigned short* __restrict__ h2pb, const float* __restrict__ b2,
        const float* __restrict__ Wa, const float* __restrict__ ba, const float* __restrict__ Wc,
        int n, float* __restrict__ out, float* __restrict__ valbuf)
{
    __shared__ float WaS[1024], WcS[32], baS[32], b2S[32];
    __shared__ float h2s[4*32], vpart[4], logit_s[128];
    const int tid = threadIdx.x;

    *(float4*)&WaS[tid*4] = *(const float4*)&Wa[tid*4];
    if (tid < 32){ WcS[tid] = Wc[tid]; baS[tid] = ba[tid]; b2S[tid] = b2[tid]; }
    __syncthreads();

    const int lane = tid & 63, wv = tid >> 6;
    const int node = blockIdx.x*4 + wv;
    const int f    = lane & 31;
    const int half = lane >> 5;
    const int j16  = lane & 15;
    const int grp  = lane & 48;
    const bool valid = node < n;

    float den = 0.f, acc = 0.f;
    if (valid){
        const float adv = ad2[node];
        const int start = rs[node], end = re[node];
        const unsigned short* hp = h2pb + f;
        int i0 = start;
        for (; i0 + 16 <= end; i0 += 16){
            int sj = csr[i0 + j16];
            float e = __expf(leaky02(as2[sj] + adv));
            den += e;
            #pragma unroll
            for (int jj = 0; jj < 8; jj++){
                int j = 2*jj + half;
                float ej = __shfl(e,  grp + j, 64);
                int   s2 = __shfl(sj, grp + j, 64);
                acc += ej * bf1(hp[s2*32]);
            }
        }
        int c = end - i0;
        if (c > 0){
            int jj = (j16 < c) ? j16 : (c-1);
            int sj = csr[i0 + jj];
            float e = __expf(leaky02(as2[sj] + adv));
            if (j16 < c) den += e;
            for (int j = half; j < c; j += 8){
                #pragma unroll
                for (int u = 0; u < 4; u++){
                    int je = j + 2*u;
                    int jc = (je < c) ? je : (c-1);
                    float ej = __shfl(e,  grp + (jc & 15), 64);
                    int   s2 = __shfl(sj, grp + (jc & 15), 64);
                    ej = (je < c) ? ej : 0.f;
                    acc += ej * bf1(hp[s2*32]);
                }
            }
        }
    }
    den += __shfl_xor(den, 1, 64);
    den += __shfl_xor(den, 2, 64);
    den += __shfl_xor(den, 4, 64);
    den += __shfl_xor(den, 8, 64);
    acc += __shfl_xor(acc, 32, 64);

    if (valid && half == 0){
        float o = acc/den + b2S[f];
        o = o > 0.f ? o : expm1f(o);
        h2s[wv*32 + f] = o;           // same-wave LDS write; read below
    }

    // value partial: lanes of half 0 reduce h2·Wc
    {
        float t = 0.f;
        if (valid && half == 0) t = h2s[wv*32 + f] * WcS[f];
        t += __shfl_xor(t, 1, 64);
        t += __shfl_xor(t, 2, 64);
        t += __shfl_xor(t, 4, 64);
        t += __shfl_xor(t, 8, 64);
        t += __shfl_xor(t, 16, 64);
        if (lane == 0) vpart[wv] = valid ? t : 0.f;
    }

    // logits: agent a = lane&31; each half does 16 channels, combine across halves
    {
        float pa = 0.f;
        if (valid){
            int a = lane & 31;
            #pragma unroll
            for (int cc = 0; cc < 16; cc++){
                int c = half*16 + cc;
                pa += h2s[wv*32 + c] * WaS[c*32 + a];
            }
        }
        pa += __shfl_xor(pa, 32, 64);
        if (valid && half == 0) logit_s[wv*32 + (lane & 31)] = pa + baS[lane & 31];
    }
    __syncthreads();

    // store: 16B chunks (4 consecutive nodes per agent)
    if (tid < 128){
        int a = tid >> 2, nd = tid & 3;
        int nodeS = blockIdx.x*4 + nd;
        if (nodeS < n) out[(size_t)a*n + nodeS] = logit_s[nd*32 + a];
    }
    // fire-and-forget value partial (device-scope atomic; NO fence)
    if (tid == 0){
        float bp = vpart[0] + vpart[1] + vpart[2] + vpart[3];
        atomicAdd(&valbuf[(blockIdx.x & 63)*32], bp);
    }
}

// ---------------- L8: final value reduce (atomic reads for cross-XCD coherence) ----------------
__global__ void k_val(float* __restrict__ valbuf, const float* __restrict__ bc,
                      int n, float* __restrict__ out)
{
    int tid = threadIdx.x;
    float v = atomicAdd(&valbuf[tid*32], 0.f);
    v += __shfl_xor(v, 1, 64);
    v += __shfl_xor(v, 2, 64);
    v += __shfl_xor(v, 4, 64);
    v += __shfl_xor(v, 8, 64);
    v += __shfl_xor(v, 16, 64);
    v += __shfl_xor(v, 32, 64);
    if (tid == 0) out[(size_t)32*n] = v*(1.0f/n) + bc[0];
}

extern "C" void kernel_launch(void* const* d_in, const int* in_sizes, int n_in,
                              void* d_out, int out_size, void* d_ws, size_t ws_size,
                              hipStream_t stream)
{
    const float* x   = (const float*)d_in[0];
    const int*   ei  = (const int*)d_in[1];
    const float* W1  = (const float*)d_in[2];
    const float* a1s = (const float*)d_in[3];
    const float* a1d = (const float*)d_in[4];
    const float* b1  = (const float*)d_in[5];
    const float* W2  = (const float*)d_in[6];
    const float* a2s = (const float*)d_in[7];
    const float* a2d = (const float*)d_in[8];
    const float* b2  = (const float*)d_in[9];
    const float* Wa  = (const float*)d_in[10];
    const float* ba  = (const float*)d_in[11];
    const float* Wc  = (const float*)d_in[12];
    const float* bc  = (const float*)d_in[13];
    float* out = (float*)d_out;

    const int N  = in_sizes[0] / 128;
    const int E  = in_sizes[1] / 2;
    const int E2 = E + N;
    const int nbT = (E2 + TILE - 1) / TILE;   // sort tiles
    const int nbB = (N + 255) / 256;          // buckets
    const int nbG = (N + 63) / 64;            // gemm blocks
    const int nbAgg = (N + 3) / 4;            // agg blocks

    // workspace layout (256B-aligned chunks)
    char* base = (char*)d_ws;
    auto alloc = [&](size_t bytes) -> char* {
        char* p = base; base += (bytes + 255) & ~(size_t)255; return p;
    };
    float* as1    = (float*)alloc((size_t)N*4*4);
    float* ad1    = (float*)alloc((size_t)N*4*4);
    float* as2    = (float*)alloc((size_t)N*4);
    float* ad2    = (float*)alloc((size_t)N*4);
    int* counts   = (int*)alloc((size_t)nbT*256*4);
    int* digTot   = (int*)alloc(256*4);
    int* base257  = (int*)alloc(257*4);
    int* done     = (int*)alloc(256);
    float* valbuf = (float*)alloc(64*32*4);
    int* rs       = (int*)alloc((size_t)N*4);
    int* re       = (int*)alloc((size_t)N*4);
    int* csr      = (int*)alloc((size_t)E2*4);
    unsigned int* buck = (unsigned int*)alloc((size_t)E2*4);
    unsigned short* h1b  = (unsigned short*)alloc((size_t)N*128*2);
    unsigned short* h1ob = (unsigned short*)alloc((size_t)N*128*2);
    unsigned short* h2pb = (unsigned short*)alloc((size_t)N*32*2);

    k_fused1<<<nbG + nbT, 256, 0, stream>>>(x, W1, a1s, a1d, h1b, as1, ad1, N,
                                            ei, E, E2, counts, nbT, nbG, done, valbuf);
    k_scan<<<256, 256, 0, stream>>>(counts, nbT, digTot, base257, done);
    k_bucket<<<nbT, 256, 0, stream>>>(ei, E, E2, counts, nbT, base257, buck);
    k_p2<<<nbB, 256, 0, stream>>>(buck, base257, N, csr, rs, re);
    k_agg1<<<nbAgg, 256, 0, stream>>>(rs, re, csr, as1, ad1, h1b, b1, h1ob, N);
    k_gemm2<<<nbG, 256, 0, stream>>>(h1ob, W2, a2s, a2d, h2pb, as2, ad2, N);
    k_agg2h<<<nbAgg, 256, 0, stream>>>(rs, re, csr, as2, ad2, h2pb, b2,
                                       Wa, ba, Wc, N, out, valbuf);
    k_val<<<1, 64, 0, stream>>>(valbuf, bc, N, out);
}